// Round 1
// baseline (1640.341 us; speedup 1.0000x reference)
//
#include <hip/hip_runtime.h>
#include <math.h>

// DrBC: encoder -> 5x(GCN-aggregate + GRU + l2norm, running max) -> decoder.
// All fp32. CSR built per call (deterministic up to fp sum order from atomic
// scatter position assignment, which is far below threshold).

#define NTHREADS 256

// ---------------- CSR build ----------------

__global__ void count_deg(const int* __restrict__ col, int* deg, int E) {
  int e = blockIdx.x * NTHREADS + threadIdx.x;
  if (e < E) atomicAdd(&deg[col[e]], 1);
}

__global__ void compute_dinv(const int* __restrict__ deg, float* __restrict__ dinv, int n) {
  int i = blockIdx.x * NTHREADS + threadIdx.x;
  if (i < n) dinv[i] = rsqrtf((float)deg[i] + 1.0f);
}

// Single-block exclusive scan over n counts -> row_ptr[0..n], row_ptr[n] = total.
__global__ void scan1024(const int* __restrict__ cnt, int* __restrict__ row_ptr, int n) {
  __shared__ int sums[1024];
  int t = threadIdx.x;
  int chunk = (n + 1023) >> 10;
  int start = t * chunk;
  int end = start + chunk; if (end > n) end = n;
  int s = 0;
  for (int i = start; i < end; ++i) s += cnt[i];
  sums[t] = s;
  __syncthreads();
  for (int off = 1; off < 1024; off <<= 1) {
    int v = sums[t];
    int a = (t >= off) ? sums[t - off] : 0;
    __syncthreads();
    sums[t] = v + a;
    __syncthreads();
  }
  int excl = (t == 0) ? 0 : sums[t - 1];
  for (int i = start; i < end; ++i) { row_ptr[i] = excl; excl += cnt[i]; }
  if (t == 1023) row_ptr[n] = sums[1023];
}

__global__ void scatter_edges(const int* __restrict__ row, const int* __restrict__ col,
                              const float* __restrict__ dinv, int* cursor,
                              int* __restrict__ src, float* __restrict__ wgt, int E) {
  int e = blockIdx.x * NTHREADS + threadIdx.x;
  if (e >= E) return;
  int r = row[e], c = col[e];
  int p = atomicAdd(&cursor[c], 1);
  src[p] = r;
  wgt[p] = dinv[r] * dinv[c];
}

// ---------------- weight transposes (coalesced access in hot loops) ----------------

// in: [L][384][128] -> out: [L][128][384]
__global__ void transpose_w(const float* __restrict__ in, float* __restrict__ out, int total) {
  int idx = blockIdx.x * NTHREADS + threadIdx.x;
  if (idx >= total) return;
  int l = idx / 49152, rem = idx % 49152;
  int k = rem / 384, c = rem % 384;
  out[idx] = in[l * 49152 + c * 128 + k];
}

// in [64][128] -> out [128][64]
__global__ void transpose_wh(const float* __restrict__ in, float* __restrict__ out) {
  int idx = blockIdx.x * NTHREADS + threadIdx.x;
  if (idx >= 8192) return;
  int k = idx >> 6, i = idx & 63;
  out[idx] = in[i * 128 + k];
}

// ---------------- encoder: h0 = l2norm(relu(x @ W^T + b)), zmax = h0 ----------------

__global__ void encoder(const float* __restrict__ x, const float* __restrict__ W,
                        const float* __restrict__ b, float* __restrict__ h,
                        float* __restrict__ zmax, int n) {
  int node = blockIdx.x * 4 + (threadIdx.x >> 6);
  int lane = threadIdx.x & 63;
  if (node >= n) return;
  float x0 = x[node * 3 + 0], x1 = x[node * 3 + 1], x2 = x[node * 3 + 2];
  int j0 = lane, j1 = lane + 64;
  float v0 = fmaxf(fmaf(W[j0 * 3 + 2], x2, fmaf(W[j0 * 3 + 1], x1, fmaf(W[j0 * 3], x0, b[j0]))), 0.f);
  float v1 = fmaxf(fmaf(W[j1 * 3 + 2], x2, fmaf(W[j1 * 3 + 1], x1, fmaf(W[j1 * 3], x0, b[j1]))), 0.f);
  float ss = v0 * v0 + v1 * v1;
#pragma unroll
  for (int sh = 32; sh > 0; sh >>= 1) ss += __shfl_down(ss, sh);
  ss = __shfl(ss, 0);
  float sc = 1.0f / fmaxf(sqrtf(ss), 1e-12f);
  size_t base = (size_t)node * 128;
  float o0 = v0 * sc, o1 = v1 * sc;
  h[base + j0] = o0;
  h[base + j1] = o1;
  zmax[base + j0] = o0;
  zmax[base + j1] = o1;
}

// ---------------- aggregation: agg[v] = sum_{e: col==v} w_e * h[src_e] ----------------

__global__ void aggregate(const int* __restrict__ row_ptr, const int* __restrict__ src,
                          const float* __restrict__ wgt, const float* __restrict__ h,
                          float* __restrict__ agg, int n) {
  int node = blockIdx.x * 4 + (threadIdx.x >> 6);
  int lane = threadIdx.x & 63;
  if (node >= n) return;
  float a0 = 0.f, a1 = 0.f;
  int pb = row_ptr[node], pe = row_ptr[node + 1];
  for (int p = pb; p < pe; ++p) {
    int s = src[p];
    float w = wgt[p];
    const float* hp = h + (size_t)s * 128;
    a0 = fmaf(w, hp[lane], a0);
    a1 = fmaf(w, hp[lane + 64], a1);
  }
  size_t base = (size_t)node * 128;
  agg[base + lane] = a0;
  agg[base + lane + 64] = a1;
}

// ---------------- fused GRU layer: gates + update + l2norm + running max ----------------
// Block: 256 threads, 16 nodes. wT/uT are [128][384] (k-major, coalesced over j).

__global__ __launch_bounds__(256) void gru_layer(
    const float* __restrict__ agg, float* __restrict__ h, float* __restrict__ zmax,
    const float* __restrict__ wT, const float* __restrict__ uT,
    const float* __restrict__ bih, const float* __restrict__ bhh, int n) {
  __shared__ float aS[16][128];
  __shared__ float hS[16][128];
  __shared__ float hnS[16][128];
  int tid = threadIdx.x;
  int base = blockIdx.x * 16;
  if (base >= n) return;  // grid is exact for N=50000
  {
    const float4* a4 = (const float4*)(agg + (size_t)base * 128);
    const float4* h4 = (const float4*)(h + (size_t)base * 128);
    float4* aS4 = (float4*)&aS[0][0];
    float4* hS4 = (float4*)&hS[0][0];
#pragma unroll
    for (int i = 0; i < 2; ++i) {
      aS4[tid + i * 256] = a4[tid + i * 256];
      hS4[tid + i * 256] = h4[tid + i * 256];
    }
  }
  __syncthreads();
  int j = tid & 127;
  int g = tid >> 7;  // 2 node-groups of 8
  float acc0[8], acc1[8], acc2[8], acc3[8], acc4[8], acc5[8];
#pragma unroll
  for (int m = 0; m < 8; ++m) { acc0[m] = acc1[m] = acc2[m] = acc3[m] = acc4[m] = acc5[m] = 0.f; }
#pragma unroll 4
  for (int k = 0; k < 128; ++k) {
    float w0 = wT[k * 384 + j];
    float w1 = wT[k * 384 + 128 + j];
    float w2 = wT[k * 384 + 256 + j];
    float u0 = uT[k * 384 + j];
    float u1 = uT[k * 384 + 128 + j];
    float u2 = uT[k * 384 + 256 + j];
#pragma unroll
    for (int m = 0; m < 8; ++m) {
      float a = aS[g * 8 + m][k];
      float hh = hS[g * 8 + m][k];
      acc0[m] = fmaf(w0, a, acc0[m]);
      acc1[m] = fmaf(w1, a, acc1[m]);
      acc2[m] = fmaf(w2, a, acc2[m]);
      acc3[m] = fmaf(u0, hh, acc3[m]);
      acc4[m] = fmaf(u1, hh, acc4[m]);
      acc5[m] = fmaf(u2, hh, acc5[m]);
    }
  }
  float br = bih[j], bz = bih[128 + j], bnn = bih[256 + j];
  float cr = bhh[j], cz = bhh[128 + j], cn = bhh[256 + j];
#pragma unroll
  for (int m = 0; m < 8; ++m) {
    int node = g * 8 + m;
    float rg = 1.f / (1.f + __expf(-((acc0[m] + br) + (acc3[m] + cr))));
    float zg = 1.f / (1.f + __expf(-((acc1[m] + bz) + (acc4[m] + cz))));
    float ng = tanhf((acc2[m] + bnn) + rg * (acc5[m] + cn));
    float hv = hS[node][j];
    hnS[node][j] = (1.f - zg) * ng + zg * hv;
  }
  __syncthreads();
  int wv = tid >> 6, lane = tid & 63;
#pragma unroll
  for (int m = 0; m < 4; ++m) {
    int node = wv * 4 + m;
    float v0 = hnS[node][lane], v1 = hnS[node][lane + 64];
    float ss = v0 * v0 + v1 * v1;
#pragma unroll
    for (int sh = 32; sh > 0; sh >>= 1) ss += __shfl_down(ss, sh);
    ss = __shfl(ss, 0);
    float sc = 1.f / fmaxf(sqrtf(ss), 1e-12f);
    size_t gb = (size_t)(base + node) * 128;
    float o0 = v0 * sc, o1 = v1 * sc;
    h[gb + lane] = o0;
    h[gb + lane + 64] = o1;
    zmax[gb + lane] = fmaxf(zmax[gb + lane], o0);
    zmax[gb + lane + 64] = fmaxf(zmax[gb + lane + 64], o1);
  }
}

// ---------------- decoder: out = relu(z @ Wh^T + bh) @ Wo^T + bo ----------------

__global__ void decoder(const float* __restrict__ z, const float* __restrict__ WhT,
                        const float* __restrict__ bh, const float* __restrict__ Wo,
                        const float* __restrict__ bo, float* __restrict__ out, int n) {
  __shared__ float zS[4][128];
  int wv = threadIdx.x >> 6, lane = threadIdx.x & 63;
  int node = blockIdx.x * 4 + wv;
  if (node >= n) return;  // grid exact for N=50000 -> all waves reach barrier
  zS[wv][lane] = z[(size_t)node * 128 + lane];
  zS[wv][lane + 64] = z[(size_t)node * 128 + lane + 64];
  __syncthreads();
  float acc = bh[lane];
#pragma unroll 4
  for (int k = 0; k < 128; ++k) acc = fmaf(zS[wv][k], WhT[k * 64 + lane], acc);
  float hid = fmaxf(acc, 0.f);
  float val = hid * Wo[lane];
#pragma unroll
  for (int sh = 32; sh > 0; sh >>= 1) val += __shfl_down(val, sh);
  if (lane == 0) out[node] = val + bo[0];
}

// ---------------- launch ----------------

extern "C" void kernel_launch(void* const* d_in, const int* in_sizes, int n_in,
                              void* d_out, int out_size, void* d_ws, size_t ws_size,
                              hipStream_t stream) {
  const float* x       = (const float*)d_in[0];
  const int*   edge    = (const int*)d_in[1];
  const float* W_embed = (const float*)d_in[2];
  const float* b_embed = (const float*)d_in[3];
  const float* w_ih    = (const float*)d_in[4];
  const float* w_hh    = (const float*)d_in[5];
  const float* b_ih    = (const float*)d_in[6];
  const float* b_hh    = (const float*)d_in[7];
  const float* W_hid   = (const float*)d_in[8];
  const float* b_hid   = (const float*)d_in[9];
  const float* W_out   = (const float*)d_in[10];
  const float* b_out   = (const float*)d_in[11];
  float* out = (float*)d_out;

  const int N = in_sizes[0] / 3;       // 50000
  const int E = in_sizes[1] / 2;       // 600000

  char* ws = (char*)d_ws;
  size_t off = 0;
  auto alloc = [&](size_t bytes) -> void* {
    void* p = ws + off;
    off = (off + bytes + 511) & ~(size_t)511;
    return p;
  };
  int*   deg     = (int*)alloc((size_t)N * 4);
  float* dinv    = (float*)alloc((size_t)N * 4);
  int*   row_ptr = (int*)alloc((size_t)(N + 1) * 4);
  int*   cursor  = (int*)alloc((size_t)N * 4);
  int*   srcv    = (int*)alloc((size_t)E * 4);
  float* wgtv    = (float*)alloc((size_t)E * 4);
  float* wihT    = (float*)alloc((size_t)5 * 49152 * 4);
  float* whhT    = (float*)alloc((size_t)5 * 49152 * 4);
  float* WhT     = (float*)alloc((size_t)8192 * 4);
  float* h       = (float*)alloc((size_t)N * 128 * 4);
  float* agg     = (float*)alloc((size_t)N * 128 * 4);
  float* zmax    = (float*)alloc((size_t)N * 128 * 4);

  const int* erow = edge;
  const int* ecol = edge + E;

  hipMemsetAsync(deg, 0, (size_t)N * 4, stream);
  count_deg<<<(E + NTHREADS - 1) / NTHREADS, NTHREADS, 0, stream>>>(ecol, deg, E);
  compute_dinv<<<(N + NTHREADS - 1) / NTHREADS, NTHREADS, 0, stream>>>(deg, dinv, N);
  scan1024<<<1, 1024, 0, stream>>>(deg, row_ptr, N);
  hipMemcpyAsync(cursor, row_ptr, (size_t)N * 4, hipMemcpyDeviceToDevice, stream);
  scatter_edges<<<(E + NTHREADS - 1) / NTHREADS, NTHREADS, 0, stream>>>(erow, ecol, dinv, cursor, srcv, wgtv, E);

  transpose_w<<<(245760 + NTHREADS - 1) / NTHREADS, NTHREADS, 0, stream>>>(w_ih, wihT, 245760);
  transpose_w<<<(245760 + NTHREADS - 1) / NTHREADS, NTHREADS, 0, stream>>>(w_hh, whhT, 245760);
  transpose_wh<<<32, NTHREADS, 0, stream>>>(W_hid, WhT);

  encoder<<<(N + 3) / 4, NTHREADS, 0, stream>>>(x, W_embed, b_embed, h, zmax, N);

  for (int l = 0; l < 5; ++l) {
    aggregate<<<(N + 3) / 4, NTHREADS, 0, stream>>>(row_ptr, srcv, wgtv, h, agg, N);
    gru_layer<<<(N + 15) / 16, NTHREADS, 0, stream>>>(
        agg, h, zmax, wihT + (size_t)l * 49152, whhT + (size_t)l * 49152,
        b_ih + (size_t)l * 384, b_hh + (size_t)l * 384, N);
  }

  decoder<<<(N + 3) / 4, NTHREADS, 0, stream>>>(zmax, WhT, b_hid, W_out, b_out, out, N);
}

// Round 2
// 818.213 us; speedup vs baseline: 2.0048x; 2.0048x over previous
//
#include <hip/hip_runtime.h>
#include <math.h>

// DrBC: encoder -> 5x(GCN-aggregate + GRU(MFMA bf16) + l2norm, running max) -> decoder.
// GRU matmuls on matrix cores (bf16 in, fp32 acc); carry path and norm stay fp32.

#define NTHREADS 256

typedef __attribute__((ext_vector_type(8))) short s16x8;
typedef __attribute__((ext_vector_type(4))) float f32x4;

union U8 { s16x8 v; ushort4 h[2]; int4 q; };

__device__ __forceinline__ unsigned short f2bf(float f) {
  union { float f; unsigned u; } x; x.f = f;
  unsigned u = x.u + 0x7FFFu + ((x.u >> 16) & 1u);  // RNE to bf16
  return (unsigned short)(u >> 16);
}

// ---------------- CSR build ----------------

__global__ void count_deg(const int* __restrict__ col, int* deg, int E) {
  int e = blockIdx.x * NTHREADS + threadIdx.x;
  if (e < E) atomicAdd(&deg[col[e]], 1);
}

__global__ void compute_dinv(const int* __restrict__ deg, float* __restrict__ dinv, int n) {
  int i = blockIdx.x * NTHREADS + threadIdx.x;
  if (i < n) dinv[i] = rsqrtf((float)deg[i] + 1.0f);
}

__global__ void scan1024(const int* __restrict__ cnt, int* __restrict__ row_ptr, int n) {
  __shared__ int sums[1024];
  int t = threadIdx.x;
  int chunk = (n + 1023) >> 10;
  int start = t * chunk;
  int end = start + chunk; if (end > n) end = n;
  int s = 0;
  for (int i = start; i < end; ++i) s += cnt[i];
  sums[t] = s;
  __syncthreads();
  for (int off = 1; off < 1024; off <<= 1) {
    int v = sums[t];
    int a = (t >= off) ? sums[t - off] : 0;
    __syncthreads();
    sums[t] = v + a;
    __syncthreads();
  }
  int excl = (t == 0) ? 0 : sums[t - 1];
  for (int i = start; i < end; ++i) { row_ptr[i] = excl; excl += cnt[i]; }
  if (t == 1023) row_ptr[n] = sums[1023];
}

__global__ void scatter_edges(const int* __restrict__ row, const int* __restrict__ col,
                              const float* __restrict__ dinv, int* cursor,
                              int* __restrict__ src, float* __restrict__ wgt, int E) {
  int e = blockIdx.x * NTHREADS + threadIdx.x;
  if (e >= E) return;
  int r = row[e], c = col[e];
  int p = atomicAdd(&cursor[c], 1);
  src[p] = r;
  wgt[p] = dinv[r] * dinv[c];
}

// ---------------- weight pack: MFMA B-fragment order, bf16 ----------------
// layout: [layer][ks 0..3][g 0..5][ft 0..7][lane 0..63][e 0..7] bf16
// g<3: w_ih gate g (r,z,n); g>=3: w_hh gate g-3.
// k-map sigma(e,lane) = 32*ks + (e&3) + 4*((lane>>4)&3) + 16*(e>>2)  (same map used
// for A-frag loads -> result invariant to sigma's exact correctness).

__global__ void pack_weights(const float* __restrict__ w_ih, const float* __restrict__ w_hh,
                             unsigned short* __restrict__ out) {
  int idx = blockIdx.x * NTHREADS + threadIdx.x;
  if (idx >= 491520) return;
  int e = idx & 7;
  int lane = (idx >> 3) & 63;
  int ft = (idx >> 9) & 7;
  int v = idx >> 12;
  int g = v % 6;
  int u = v / 6;
  int ks = u & 3;
  int layer = u >> 2;
  int k = 32 * ks + (e & 3) + 4 * ((lane >> 4) & 3) + 16 * (e >> 2);
  int j = 16 * ft + (lane & 15);
  const float* src = (g < 3) ? w_ih : w_hh;
  int gate = g % 6 % 3;
  float val = src[(size_t)layer * 49152 + (size_t)(gate * 128 + j) * 128 + k];
  out[idx] = f2bf(val);
}

// in [64][128] -> out [128][64]
__global__ void transpose_wh(const float* __restrict__ in, float* __restrict__ out) {
  int idx = blockIdx.x * NTHREADS + threadIdx.x;
  if (idx >= 8192) return;
  int k = idx >> 6, i = idx & 63;
  out[idx] = in[i * 128 + k];
}

// ---------------- encoder ----------------

__global__ void encoder(const float* __restrict__ x, const float* __restrict__ W,
                        const float* __restrict__ b, float* __restrict__ h,
                        float* __restrict__ zmax, int n) {
  int node = blockIdx.x * 4 + (threadIdx.x >> 6);
  int lane = threadIdx.x & 63;
  if (node >= n) return;
  float x0 = x[node * 3 + 0], x1 = x[node * 3 + 1], x2 = x[node * 3 + 2];
  int j0 = lane, j1 = lane + 64;
  float v0 = fmaxf(fmaf(W[j0 * 3 + 2], x2, fmaf(W[j0 * 3 + 1], x1, fmaf(W[j0 * 3], x0, b[j0]))), 0.f);
  float v1 = fmaxf(fmaf(W[j1 * 3 + 2], x2, fmaf(W[j1 * 3 + 1], x1, fmaf(W[j1 * 3], x0, b[j1]))), 0.f);
  float ss = v0 * v0 + v1 * v1;
#pragma unroll
  for (int sh = 32; sh > 0; sh >>= 1) ss += __shfl_down(ss, sh);
  ss = __shfl(ss, 0);
  float sc = 1.0f / fmaxf(sqrtf(ss), 1e-12f);
  size_t base = (size_t)node * 128;
  float o0 = v0 * sc, o1 = v1 * sc;
  h[base + j0] = o0;
  h[base + j1] = o1;
  zmax[base + j0] = o0;
  zmax[base + j1] = o1;
}

// ---------------- aggregation ----------------

__global__ void aggregate(const int* __restrict__ row_ptr, const int* __restrict__ src,
                          const float* __restrict__ wgt, const float* __restrict__ h,
                          float* __restrict__ agg, int n) {
  int node = blockIdx.x * 4 + (threadIdx.x >> 6);
  int lane = threadIdx.x & 63;
  if (node >= n) return;
  float a0 = 0.f, a1 = 0.f;
  int pb = row_ptr[node], pe = row_ptr[node + 1];
  for (int p = pb; p < pe; ++p) {
    int s = src[p];
    float w = wgt[p];
    const float* hp = h + (size_t)s * 128;
    a0 = fmaf(w, hp[lane], a0);
    a1 = fmaf(w, hp[lane + 64], a1);
  }
  size_t base = (size_t)node * 128;
  agg[base + lane] = a0;
  agg[base + lane + 64] = a1;
}

// ---------------- fused GRU layer via MFMA ----------------
// 1024 threads = 16 waves. Block: 64 nodes x 128 features x 6 gate-GEMMs, K=128.
// Wave w: mh=w&1 (rows 32mh..+32, 2 m-tiles), fh=w>>1 (features 16fh..+16).

__global__ __launch_bounds__(1024) void gru_mfma(
    const float* __restrict__ agg, float* __restrict__ h, float* __restrict__ zmax,
    const int4* __restrict__ wpk, const float* __restrict__ bih,
    const float* __restrict__ bhh, int n) {
  __shared__ unsigned short aggSb[64 * 132];  // bf16, +4 pad -> 4-way b64 (floor)
  __shared__ unsigned short hSb[64 * 132];
  __shared__ float partS[64 * 8];
  __shared__ float scv[64];
  int tid = threadIdx.x;
  int base = blockIdx.x * 64;

  // stage agg,h -> LDS bf16 (convert once here, not per-fragment)
#pragma unroll
  for (int rep = 0; rep < 2; ++rep) {
    int idx = tid + rep * 1024;
    int row = idx >> 5, c4 = idx & 31;
    int gr = base + row; if (gr > n - 1) gr = n - 1;
    float4 va = ((const float4*)agg)[(size_t)gr * 32 + c4];
    float4 vh = ((const float4*)h)[(size_t)gr * 32 + c4];
    ushort4 ua; ua.x = f2bf(va.x); ua.y = f2bf(va.y); ua.z = f2bf(va.z); ua.w = f2bf(va.w);
    ushort4 uh; uh.x = f2bf(vh.x); uh.y = f2bf(vh.y); uh.z = f2bf(vh.z); uh.w = f2bf(vh.w);
    *(ushort4*)&aggSb[row * 132 + c4 * 4] = ua;
    *(ushort4*)&hSb[row * 132 + c4 * 4] = uh;
  }
  __syncthreads();

  int w = tid >> 6, l = tid & 63;
  int mh = w & 1, fh = w >> 1;
  int lr = l & 15, lg = l >> 4;

  f32x4 acc[2][6];
#pragma unroll
  for (int mt = 0; mt < 2; ++mt)
#pragma unroll
    for (int g = 0; g < 6; ++g) { acc[mt][g][0] = 0.f; acc[mt][g][1] = 0.f; acc[mt][g][2] = 0.f; acc[mt][g][3] = 0.f; }

#pragma unroll
  for (int ks = 0; ks < 4; ++ks) {
    U8 fa[2], fhh[2];
#pragma unroll
    for (int mt = 0; mt < 2; ++mt) {
      int boff = (mh * 32 + mt * 16 + lr) * 132 + ks * 32 + lg * 4;
      fa[mt].h[0] = *(const ushort4*)&aggSb[boff];
      fa[mt].h[1] = *(const ushort4*)&aggSb[boff + 16];
      fhh[mt].h[0] = *(const ushort4*)&hSb[boff];
      fhh[mt].h[1] = *(const ushort4*)&hSb[boff + 16];
    }
#pragma unroll
    for (int g = 0; g < 6; ++g) {
      U8 bw; bw.q = wpk[((ks * 6 + g) * 8 + fh) * 64 + l];
      const U8& a0 = (g < 3) ? fa[0] : fhh[0];
      const U8& a1 = (g < 3) ? fa[1] : fhh[1];
      acc[0][g] = __builtin_amdgcn_mfma_f32_16x16x32_bf16(a0.v, bw.v, acc[0][g], 0, 0, 0);
      acc[1][g] = __builtin_amdgcn_mfma_f32_16x16x32_bf16(a1.v, bw.v, acc[1][g], 0, 0, 0);
    }
  }

  // gates + carry (fp32 hv from global, L2-hot) ; C/D map: col=lane&15, row=4*(lane>>4)+reg
  int jj = fh * 16 + lr;
  float br = bih[jj], bz = bih[128 + jj], bn = bih[256 + jj];
  float cr = bhh[jj], cz = bhh[128 + jj], cn = bhh[256 + jj];
  float hn_out[2][4];
#pragma unroll
  for (int mt = 0; mt < 2; ++mt)
#pragma unroll
    for (int e = 0; e < 4; ++e) {
      int row = mh * 32 + mt * 16 + lg * 4 + e;
      float ir = acc[mt][0][e], iz = acc[mt][1][e], inn = acc[mt][2][e];
      float hr = acc[mt][3][e], hz = acc[mt][4][e], hnv = acc[mt][5][e];
      float r = 1.f / (1.f + __expf(-(ir + hr + br + cr)));
      float z = 1.f / (1.f + __expf(-(iz + hz + bz + cz)));
      float ng = tanhf(inn + bn + r * (hnv + cn));
      int gr = base + row; int cgr = (gr > n - 1) ? (n - 1) : gr;
      float hv = h[(size_t)cgr * 128 + jj];
      float hn = (1.f - z) * ng + z * hv;
      hn_out[mt][e] = hn;
      float p = hn * hn;
      p += __shfl_xor(p, 1);
      p += __shfl_xor(p, 2);
      p += __shfl_xor(p, 4);
      p += __shfl_xor(p, 8);
      if (lr == 0) partS[row * 8 + fh] = p;
    }
  __syncthreads();
  if (tid < 64) {
    float ss = 0.f;
#pragma unroll
    for (int f = 0; f < 8; ++f) ss += partS[tid * 8 + f];
    scv[tid] = 1.f / fmaxf(sqrtf(ss), 1e-12f);
  }
  __syncthreads();
#pragma unroll
  for (int mt = 0; mt < 2; ++mt)
#pragma unroll
    for (int e = 0; e < 4; ++e) {
      int row = mh * 32 + mt * 16 + lg * 4 + e;
      int gr = base + row;
      if (gr < n) {
        float v = hn_out[mt][e] * scv[row];
        size_t o = (size_t)gr * 128 + jj;
        h[o] = v;
        zmax[o] = fmaxf(zmax[o], v);
      }
    }
}

// ---------------- decoder ----------------

__global__ void decoder(const float* __restrict__ z, const float* __restrict__ WhT,
                        const float* __restrict__ bh, const float* __restrict__ Wo,
                        const float* __restrict__ bo, float* __restrict__ out, int n) {
  __shared__ float zS[4][128];
  int wv = threadIdx.x >> 6, lane = threadIdx.x & 63;
  int node = blockIdx.x * 4 + wv;
  if (node >= n) return;  // grid exact for N=50000
  zS[wv][lane] = z[(size_t)node * 128 + lane];
  zS[wv][lane + 64] = z[(size_t)node * 128 + lane + 64];
  __syncthreads();
  float acc = bh[lane];
#pragma unroll 4
  for (int k = 0; k < 128; ++k) acc = fmaf(zS[wv][k], WhT[k * 64 + lane], acc);
  float hid = fmaxf(acc, 0.f);
  float val = hid * Wo[lane];
#pragma unroll
  for (int sh = 32; sh > 0; sh >>= 1) val += __shfl_down(val, sh);
  if (lane == 0) out[node] = val + bo[0];
}

// ---------------- launch ----------------

extern "C" void kernel_launch(void* const* d_in, const int* in_sizes, int n_in,
                              void* d_out, int out_size, void* d_ws, size_t ws_size,
                              hipStream_t stream) {
  const float* x       = (const float*)d_in[0];
  const int*   edge    = (const int*)d_in[1];
  const float* W_embed = (const float*)d_in[2];
  const float* b_embed = (const float*)d_in[3];
  const float* w_ih    = (const float*)d_in[4];
  const float* w_hh    = (const float*)d_in[5];
  const float* b_ih    = (const float*)d_in[6];
  const float* b_hh    = (const float*)d_in[7];
  const float* W_hid   = (const float*)d_in[8];
  const float* b_hid   = (const float*)d_in[9];
  const float* W_out   = (const float*)d_in[10];
  const float* b_out   = (const float*)d_in[11];
  float* out = (float*)d_out;

  const int N = in_sizes[0] / 3;       // 50000
  const int E = in_sizes[1] / 2;       // 600000

  char* ws = (char*)d_ws;
  size_t off = 0;
  auto alloc = [&](size_t bytes) -> void* {
    void* p = ws + off;
    off = (off + bytes + 511) & ~(size_t)511;
    return p;
  };
  int*   deg     = (int*)alloc((size_t)N * 4);
  float* dinv    = (float*)alloc((size_t)N * 4);
  int*   row_ptr = (int*)alloc((size_t)(N + 1) * 4);
  int*   cursor  = (int*)alloc((size_t)N * 4);
  int*   srcv    = (int*)alloc((size_t)E * 4);
  float* wgtv    = (float*)alloc((size_t)E * 4);
  unsigned short* wpack = (unsigned short*)alloc((size_t)491520 * 2);
  float* WhT     = (float*)alloc((size_t)8192 * 4);
  float* h       = (float*)alloc((size_t)N * 128 * 4);
  float* agg     = (float*)alloc((size_t)N * 128 * 4);
  float* zmax    = (float*)alloc((size_t)N * 128 * 4);

  const int* erow = edge;
  const int* ecol = edge + E;

  hipMemsetAsync(deg, 0, (size_t)N * 4, stream);
  count_deg<<<(E + NTHREADS - 1) / NTHREADS, NTHREADS, 0, stream>>>(ecol, deg, E);
  compute_dinv<<<(N + NTHREADS - 1) / NTHREADS, NTHREADS, 0, stream>>>(deg, dinv, N);
  scan1024<<<1, 1024, 0, stream>>>(deg, row_ptr, N);
  hipMemcpyAsync(cursor, row_ptr, (size_t)N * 4, hipMemcpyDeviceToDevice, stream);
  scatter_edges<<<(E + NTHREADS - 1) / NTHREADS, NTHREADS, 0, stream>>>(erow, ecol, dinv, cursor, srcv, wgtv, E);

  pack_weights<<<(491520 + NTHREADS - 1) / NTHREADS, NTHREADS, 0, stream>>>(w_ih, w_hh, wpack);
  transpose_wh<<<32, NTHREADS, 0, stream>>>(W_hid, WhT);

  encoder<<<(N + 3) / 4, NTHREADS, 0, stream>>>(x, W_embed, b_embed, h, zmax, N);

  for (int l = 0; l < 5; ++l) {
    aggregate<<<(N + 3) / 4, NTHREADS, 0, stream>>>(row_ptr, srcv, wgtv, h, agg, N);
    gru_mfma<<<(N + 63) / 64, 1024, 0, stream>>>(
        agg, h, zmax, (const int4*)(wpack + (size_t)l * 98304),
        b_ih + (size_t)l * 384, b_hh + (size_t)l * 384, N);
  }

  decoder<<<(N + 3) / 4, NTHREADS, 0, stream>>>(zmax, WhT, b_hid, W_out, b_out, out, N);
}

// Round 3
// 722.577 us; speedup vs baseline: 2.2701x; 1.1324x over previous
//
#include <hip/hip_runtime.h>
#include <math.h>

// DrBC: encoder -> 5x(GCN-aggregate(bf16) + GRU(MFMA bf16) + l2norm, running max bf16) -> decoder.
// fp32 carry path + l2norm; bf16 storage for h/agg/zmax streams.

#define NTHREADS 256
#define SCAN_CHUNK 1024

typedef __attribute__((ext_vector_type(8))) short s16x8;
typedef __attribute__((ext_vector_type(4))) float f32x4;

union U8 { s16x8 v; ushort4 h[2]; int4 q; };

__device__ __forceinline__ unsigned short f2bf(float f) {
  union { float f; unsigned u; } x; x.f = f;
  unsigned u = x.u + 0x7FFFu + ((x.u >> 16) & 1u);  // RNE to bf16
  return (unsigned short)(u >> 16);
}
__device__ __forceinline__ float bf2f(unsigned short s) {
  union { unsigned u; float f; } x; x.u = ((unsigned)s) << 16;
  return x.f;
}

// ---------------- CSR build ----------------

__global__ void count_deg(const int* __restrict__ col, int* deg, int E) {
  int e = blockIdx.x * NTHREADS + threadIdx.x;
  if (e < E) atomicAdd(&deg[col[e]], 1);
}

__global__ void compute_dinv(const int* __restrict__ deg, float* __restrict__ dinv, int n) {
  int i = blockIdx.x * NTHREADS + threadIdx.x;
  if (i < n) dinv[i] = rsqrtf((float)deg[i] + 1.0f);
}

// 3-phase parallel exclusive scan over n counts.
__global__ void block_reduce(const int* __restrict__ cnt, int* __restrict__ bsum, int n) {
  __shared__ int red[NTHREADS];
  int b = blockIdx.x, t = threadIdx.x;
  int base = b * SCAN_CHUNK + t * 4;
  int s = 0;
#pragma unroll
  for (int i = 0; i < 4; ++i) { int idx = base + i; if (idx < n) s += cnt[idx]; }
  red[t] = s;
  __syncthreads();
  for (int off = NTHREADS / 2; off > 0; off >>= 1) {
    if (t < off) red[t] += red[t + off];
    __syncthreads();
  }
  if (t == 0) bsum[b] = red[0];
}

// 64 threads (1 wave); nb <= 64.
__global__ void scan_partials(const int* __restrict__ bsum, int* __restrict__ boff,
                              int* __restrict__ row_ptr_n, int nb) {
  int t = threadIdx.x;
  int s = (t < nb) ? bsum[t] : 0;
  int orig = s;
#pragma unroll
  for (int off = 1; off < 64; off <<= 1) {
    int v = __shfl_up(s, off);
    if (t >= off) s += v;
  }
  if (t < nb) boff[t] = s - orig;
  if (t == nb - 1) *row_ptr_n = s;
}

__global__ void scan_final(const int* __restrict__ cnt, const int* __restrict__ boff,
                           int* __restrict__ row_ptr, int n) {
  __shared__ int sums[NTHREADS];
  int b = blockIdx.x, t = threadIdx.x;
  int base = b * SCAN_CHUNK + t * 4;
  int v[4];
  int s = 0;
#pragma unroll
  for (int i = 0; i < 4; ++i) { int idx = base + i; v[i] = (idx < n) ? cnt[idx] : 0; s += v[i]; }
  sums[t] = s;
  __syncthreads();
  for (int off = 1; off < NTHREADS; off <<= 1) {
    int a = (t >= off) ? sums[t - off] : 0;
    __syncthreads();
    sums[t] += a;
    __syncthreads();
  }
  int run = boff[b] + sums[t] - s;  // exclusive prefix for this thread's chunk
#pragma unroll
  for (int i = 0; i < 4; ++i) {
    int idx = base + i;
    if (idx < n) row_ptr[idx] = run;
    run += v[i];
  }
}

__global__ void scatter_edges(const int* __restrict__ row, const int* __restrict__ col,
                              const float* __restrict__ dinv, int* cursor,
                              int* __restrict__ src, float* __restrict__ wgt, int E) {
  int e = blockIdx.x * NTHREADS + threadIdx.x;
  if (e >= E) return;
  int r = row[e], c = col[e];
  int p = atomicAdd(&cursor[c], 1);
  src[p] = r;
  wgt[p] = dinv[r] * dinv[c];
}

// ---------------- weight pack: MFMA B-fragment order, bf16 ----------------
// layout: [layer][ks 0..3][g 0..5][ft 0..7][lane 0..63][e 0..7] bf16
// k-map sigma(e,lane) = 32*ks + (e&3) + 4*((lane>>4)&3) + 16*(e>>2) (same map on A side
// -> result invariant to sigma's exact correctness).

__global__ void pack_weights(const float* __restrict__ w_ih, const float* __restrict__ w_hh,
                             unsigned short* __restrict__ out) {
  int idx = blockIdx.x * NTHREADS + threadIdx.x;
  if (idx >= 491520) return;
  int e = idx & 7;
  int lane = (idx >> 3) & 63;
  int ft = (idx >> 9) & 7;
  int v = idx >> 12;
  int g = v % 6;
  int u = v / 6;
  int ks = u & 3;
  int layer = u >> 2;
  int k = 32 * ks + (e & 3) + 4 * ((lane >> 4) & 3) + 16 * (e >> 2);
  int j = 16 * ft + (lane & 15);
  const float* src = (g < 3) ? w_ih : w_hh;
  int gate = g % 3;
  float val = src[(size_t)layer * 49152 + (size_t)(gate * 128 + j) * 128 + k];
  out[idx] = f2bf(val);
}

// in [64][128] -> out [128][64]
__global__ void transpose_wh(const float* __restrict__ in, float* __restrict__ out) {
  int idx = blockIdx.x * NTHREADS + threadIdx.x;
  if (idx >= 8192) return;
  int k = idx >> 6, i = idx & 63;
  out[idx] = in[i * 128 + k];
}

// ---------------- encoder ----------------

__global__ void encoder(const float* __restrict__ x, const float* __restrict__ W,
                        const float* __restrict__ b, float* __restrict__ h,
                        unsigned short* __restrict__ hb, unsigned short* __restrict__ zmaxb,
                        int n) {
  int node = blockIdx.x * 4 + (threadIdx.x >> 6);
  int lane = threadIdx.x & 63;
  if (node >= n) return;
  float x0 = x[node * 3 + 0], x1 = x[node * 3 + 1], x2 = x[node * 3 + 2];
  int j0 = lane, j1 = lane + 64;
  float v0 = fmaxf(fmaf(W[j0 * 3 + 2], x2, fmaf(W[j0 * 3 + 1], x1, fmaf(W[j0 * 3], x0, b[j0]))), 0.f);
  float v1 = fmaxf(fmaf(W[j1 * 3 + 2], x2, fmaf(W[j1 * 3 + 1], x1, fmaf(W[j1 * 3], x0, b[j1]))), 0.f);
  float ss = v0 * v0 + v1 * v1;
#pragma unroll
  for (int sh = 32; sh > 0; sh >>= 1) ss += __shfl_down(ss, sh);
  ss = __shfl(ss, 0);
  float sc = 1.0f / fmaxf(sqrtf(ss), 1e-12f);
  size_t base = (size_t)node * 128;
  float o0 = v0 * sc, o1 = v1 * sc;
  h[base + j0] = o0;
  h[base + j1] = o1;
  unsigned short u0 = f2bf(o0), u1 = f2bf(o1);
  hb[base + j0] = u0;
  hb[base + j1] = u1;
  zmaxb[base + j0] = u0;
  zmaxb[base + j1] = u1;
}

// ---------------- aggregation (bf16 in, bf16 out, fp32 accumulate) ----------------

__global__ void aggregate(const int* __restrict__ row_ptr, const int* __restrict__ src,
                          const float* __restrict__ wgt, const unsigned short* __restrict__ hb,
                          unsigned short* __restrict__ aggb, int n) {
  int node = blockIdx.x * 4 + (threadIdx.x >> 6);
  int lane = threadIdx.x & 63;
  if (node >= n) return;
  float a0 = 0.f, a1 = 0.f;
  int pb = row_ptr[node], pe = row_ptr[node + 1];
  for (int p = pb; p < pe; ++p) {
    int s = src[p];
    float w = wgt[p];
    unsigned u = ((const unsigned*)(hb + (size_t)s * 128))[lane];
    a0 = fmaf(w, bf2f((unsigned short)(u & 0xFFFFu)), a0);
    a1 = fmaf(w, bf2f((unsigned short)(u >> 16)), a1);
  }
  unsigned o = ((unsigned)f2bf(a1) << 16) | (unsigned)f2bf(a0);
  ((unsigned*)(aggb + (size_t)node * 128))[lane] = o;
}

// ---------------- fused GRU layer via MFMA ----------------
// 1024 threads = 16 waves. Block: 64 nodes x 128 features x 6 gate-GEMMs, K=128.

__global__ __launch_bounds__(1024) void gru_mfma(
    const unsigned short* __restrict__ aggb, unsigned short* __restrict__ hb,
    float* __restrict__ h, unsigned short* __restrict__ zmaxb,
    const int4* __restrict__ wpk, const float* __restrict__ bih,
    const float* __restrict__ bhh, int n) {
  __shared__ unsigned short aggS[64 * 132];  // +4 pad: conflict-light frag reads
  __shared__ unsigned short hS[64 * 132];
  __shared__ float partS[64 * 8];
  __shared__ float scv[64];
  int tid = threadIdx.x;
  int base = blockIdx.x * 64;

#pragma unroll
  for (int rep = 0; rep < 2; ++rep) {
    int idx = tid + rep * 1024;
    int row = idx >> 5, c4 = idx & 31;
    int gr = base + row; if (gr > n - 1) gr = n - 1;
    ushort4 ua = *(const ushort4*)(aggb + (size_t)gr * 128 + c4 * 4);
    ushort4 uh = *(const ushort4*)(hb + (size_t)gr * 128 + c4 * 4);
    *(ushort4*)&aggS[row * 132 + c4 * 4] = ua;
    *(ushort4*)&hS[row * 132 + c4 * 4] = uh;
  }
  __syncthreads();

  int w = tid >> 6, l = tid & 63;
  int mh = w & 1, fh = w >> 1;
  int lr = l & 15, lg = l >> 4;

  f32x4 acc[2][6];
#pragma unroll
  for (int mt = 0; mt < 2; ++mt)
#pragma unroll
    for (int g = 0; g < 6; ++g) { acc[mt][g][0] = 0.f; acc[mt][g][1] = 0.f; acc[mt][g][2] = 0.f; acc[mt][g][3] = 0.f; }

#pragma unroll
  for (int ks = 0; ks < 4; ++ks) {
    U8 fa[2], fhh[2];
#pragma unroll
    for (int mt = 0; mt < 2; ++mt) {
      int boff = (mh * 32 + mt * 16 + lr) * 132 + ks * 32 + lg * 4;
      fa[mt].h[0] = *(const ushort4*)&aggS[boff];
      fa[mt].h[1] = *(const ushort4*)&aggS[boff + 16];
      fhh[mt].h[0] = *(const ushort4*)&hS[boff];
      fhh[mt].h[1] = *(const ushort4*)&hS[boff + 16];
    }
#pragma unroll
    for (int g = 0; g < 6; ++g) {
      U8 bw; bw.q = wpk[((ks * 6 + g) * 8 + fh) * 64 + l];
      const U8& a0 = (g < 3) ? fa[0] : fhh[0];
      const U8& a1 = (g < 3) ? fa[1] : fhh[1];
      acc[0][g] = __builtin_amdgcn_mfma_f32_16x16x32_bf16(a0.v, bw.v, acc[0][g], 0, 0, 0);
      acc[1][g] = __builtin_amdgcn_mfma_f32_16x16x32_bf16(a1.v, bw.v, acc[1][g], 0, 0, 0);
    }
  }

  // gates + fp32 carry ; C/D map: col=lane&15, row=4*(lane>>4)+reg
  int jj = fh * 16 + lr;
  float br = bih[jj], bz = bih[128 + jj], bn = bih[256 + jj];
  float cr = bhh[jj], cz = bhh[128 + jj], cn = bhh[256 + jj];
  float hn_out[2][4];
#pragma unroll
  for (int mt = 0; mt < 2; ++mt)
#pragma unroll
    for (int e = 0; e < 4; ++e) {
      int row = mh * 32 + mt * 16 + lg * 4 + e;
      float ir = acc[mt][0][e], iz = acc[mt][1][e], inn = acc[mt][2][e];
      float hr = acc[mt][3][e], hz = acc[mt][4][e], hnv = acc[mt][5][e];
      float r = 1.f / (1.f + __expf(-(ir + hr + br + cr)));
      float z = 1.f / (1.f + __expf(-(iz + hz + bz + cz)));
      float ng = tanhf(inn + bn + r * (hnv + cn));
      int gr = base + row; int cgr = (gr > n - 1) ? (n - 1) : gr;
      float hv = h[(size_t)cgr * 128 + jj];
      float hn = (1.f - z) * ng + z * hv;
      hn_out[mt][e] = hn;
      float p = hn * hn;
      p += __shfl_xor(p, 1);
      p += __shfl_xor(p, 2);
      p += __shfl_xor(p, 4);
      p += __shfl_xor(p, 8);
      if (lr == 0) partS[row * 8 + fh] = p;
    }
  __syncthreads();
  if (tid < 64) {
    float ss = 0.f;
#pragma unroll
    for (int f = 0; f < 8; ++f) ss += partS[tid * 8 + f];
    scv[tid] = 1.f / fmaxf(sqrtf(ss), 1e-12f);
  }
  __syncthreads();
#pragma unroll
  for (int mt = 0; mt < 2; ++mt)
#pragma unroll
    for (int e = 0; e < 4; ++e) {
      int row = mh * 32 + mt * 16 + lg * 4 + e;
      int gr = base + row;
      if (gr < n) {
        float v = hn_out[mt][e] * scv[row];
        size_t o = (size_t)gr * 128 + jj;
        h[o] = v;
        unsigned short ub = f2bf(v);
        hb[o] = ub;
        unsigned short zold = zmaxb[o];
        zmaxb[o] = (bf2f(ub) > bf2f(zold)) ? ub : zold;
      }
    }
}

// ---------------- decoder ----------------

__global__ void decoder(const unsigned short* __restrict__ zb, const float* __restrict__ WhT,
                        const float* __restrict__ bh, const float* __restrict__ Wo,
                        const float* __restrict__ bo, float* __restrict__ out, int n) {
  __shared__ float zS[4][128];
  int wv = threadIdx.x >> 6, lane = threadIdx.x & 63;
  int node = blockIdx.x * 4 + wv;
  if (node >= n) return;  // grid exact for N=50000
  unsigned u = ((const unsigned*)(zb + (size_t)node * 128))[lane];
  zS[wv][lane * 2] = bf2f((unsigned short)(u & 0xFFFFu));
  zS[wv][lane * 2 + 1] = bf2f((unsigned short)(u >> 16));
  __syncthreads();
  float acc = bh[lane];
#pragma unroll 4
  for (int k = 0; k < 128; ++k) acc = fmaf(zS[wv][k], WhT[k * 64 + lane], acc);
  float hid = fmaxf(acc, 0.f);
  float val = hid * Wo[lane];
#pragma unroll
  for (int sh = 32; sh > 0; sh >>= 1) val += __shfl_down(val, sh);
  if (lane == 0) out[node] = val + bo[0];
}

// ---------------- launch ----------------

extern "C" void kernel_launch(void* const* d_in, const int* in_sizes, int n_in,
                              void* d_out, int out_size, void* d_ws, size_t ws_size,
                              hipStream_t stream) {
  const float* x       = (const float*)d_in[0];
  const int*   edge    = (const int*)d_in[1];
  const float* W_embed = (const float*)d_in[2];
  const float* b_embed = (const float*)d_in[3];
  const float* w_ih    = (const float*)d_in[4];
  const float* w_hh    = (const float*)d_in[5];
  const float* b_ih    = (const float*)d_in[6];
  const float* b_hh    = (const float*)d_in[7];
  const float* W_hid   = (const float*)d_in[8];
  const float* b_hid   = (const float*)d_in[9];
  const float* W_out   = (const float*)d_in[10];
  const float* b_out   = (const float*)d_in[11];
  float* out = (float*)d_out;

  const int N = in_sizes[0] / 3;       // 50000
  const int E = in_sizes[1] / 2;       // 600000
  const int NB = (N + SCAN_CHUNK - 1) / SCAN_CHUNK;

  char* ws = (char*)d_ws;
  size_t off = 0;
  auto alloc = [&](size_t bytes) -> void* {
    void* p = ws + off;
    off = (off + bytes + 511) & ~(size_t)511;
    return p;
  };
  int*   deg     = (int*)alloc((size_t)N * 4);
  float* dinv    = (float*)alloc((size_t)N * 4);
  int*   row_ptr = (int*)alloc((size_t)(N + 1) * 4);
  int*   cursor  = (int*)alloc((size_t)N * 4);
  int*   bsum    = (int*)alloc((size_t)NB * 4);
  int*   boff    = (int*)alloc((size_t)NB * 4);
  int*   srcv    = (int*)alloc((size_t)E * 4);
  float* wgtv    = (float*)alloc((size_t)E * 4);
  unsigned short* wpack = (unsigned short*)alloc((size_t)491520 * 2);
  float* WhT     = (float*)alloc((size_t)8192 * 4);
  float* h       = (float*)alloc((size_t)N * 128 * 4);
  unsigned short* hb    = (unsigned short*)alloc((size_t)N * 128 * 2);
  unsigned short* aggb  = (unsigned short*)alloc((size_t)N * 128 * 2);
  unsigned short* zmaxb = (unsigned short*)alloc((size_t)N * 128 * 2);

  const int* erow = edge;
  const int* ecol = edge + E;

  hipMemsetAsync(deg, 0, (size_t)N * 4, stream);
  count_deg<<<(E + NTHREADS - 1) / NTHREADS, NTHREADS, 0, stream>>>(ecol, deg, E);
  compute_dinv<<<(N + NTHREADS - 1) / NTHREADS, NTHREADS, 0, stream>>>(deg, dinv, N);
  block_reduce<<<NB, NTHREADS, 0, stream>>>(deg, bsum, N);
  scan_partials<<<1, 64, 0, stream>>>(bsum, boff, row_ptr + N, NB);
  scan_final<<<NB, NTHREADS, 0, stream>>>(deg, boff, row_ptr, N);
  hipMemcpyAsync(cursor, row_ptr, (size_t)N * 4, hipMemcpyDeviceToDevice, stream);
  scatter_edges<<<(E + NTHREADS - 1) / NTHREADS, NTHREADS, 0, stream>>>(erow, ecol, dinv, cursor, srcv, wgtv, E);

  pack_weights<<<(491520 + NTHREADS - 1) / NTHREADS, NTHREADS, 0, stream>>>(w_ih, w_hh, wpack);
  transpose_wh<<<32, NTHREADS, 0, stream>>>(W_hid, WhT);

  encoder<<<(N + 3) / 4, NTHREADS, 0, stream>>>(x, W_embed, b_embed, h, hb, zmaxb, N);

  for (int l = 0; l < 5; ++l) {
    aggregate<<<(N + 3) / 4, NTHREADS, 0, stream>>>(row_ptr, srcv, wgtv, hb, aggb, N);
    gru_mfma<<<(N + 63) / 64, 1024, 0, stream>>>(
        aggb, hb, h, zmaxb, (const int4*)(wpack + (size_t)l * 98304),
        b_ih + (size_t)l * 384, b_hh + (size_t)l * 384, N);
  }

  decoder<<<(N + 3) / 4, NTHREADS, 0, stream>>>(zmaxb, WhT, b_hid, W_out, b_out, out, N);
}

// Round 4
// 549.910 us; speedup vs baseline: 2.9829x; 1.3140x over previous
//
#include <hip/hip_runtime.h>
#include <math.h>

// DrBC: encoder -> 5x(GCN-aggregate(bf16, MLP-unrolled) + GRU(MFMA bf16) + l2norm,
// running max bf16) -> decoder. fp32 carry path + l2norm.

#define NTHREADS 256
#define SCAN_CHUNK 1024

typedef __attribute__((ext_vector_type(8))) short s16x8;
typedef __attribute__((ext_vector_type(4))) float f32x4;

union U8 { s16x8 v; ushort4 h[2]; int4 q; };

__device__ __forceinline__ unsigned short f2bf(float f) {
  union { float f; unsigned u; } x; x.f = f;
  unsigned u = x.u + 0x7FFFu + ((x.u >> 16) & 1u);  // RNE to bf16
  return (unsigned short)(u >> 16);
}
__device__ __forceinline__ float bf2f(unsigned short s) {
  union { unsigned u; float f; } x; x.u = ((unsigned)s) << 16;
  return x.f;
}

// ---------------- CSR build ----------------

__global__ void count_deg(const int* __restrict__ col, int* deg, int E) {
  int e = blockIdx.x * NTHREADS + threadIdx.x;
  if (e < E) atomicAdd(&deg[col[e]], 1);
}

__global__ void compute_dinv(const int* __restrict__ deg, float* __restrict__ dinv, int n) {
  int i = blockIdx.x * NTHREADS + threadIdx.x;
  if (i < n) dinv[i] = rsqrtf((float)deg[i] + 1.0f);
}

__global__ void block_reduce(const int* __restrict__ cnt, int* __restrict__ bsum, int n) {
  __shared__ int red[NTHREADS];
  int b = blockIdx.x, t = threadIdx.x;
  int base = b * SCAN_CHUNK + t * 4;
  int s = 0;
#pragma unroll
  for (int i = 0; i < 4; ++i) { int idx = base + i; if (idx < n) s += cnt[idx]; }
  red[t] = s;
  __syncthreads();
  for (int off = NTHREADS / 2; off > 0; off >>= 1) {
    if (t < off) red[t] += red[t + off];
    __syncthreads();
  }
  if (t == 0) bsum[b] = red[0];
}

// 64 threads (1 wave); nb <= 64.
__global__ void scan_partials(const int* __restrict__ bsum, int* __restrict__ boff,
                              int* __restrict__ row_ptr_n, int nb) {
  int t = threadIdx.x;
  int s = (t < nb) ? bsum[t] : 0;
  int orig = s;
#pragma unroll
  for (int off = 1; off < 64; off <<= 1) {
    int v = __shfl_up(s, off);
    if (t >= off) s += v;
  }
  if (t < nb) boff[t] = s - orig;
  if (t == nb - 1) *row_ptr_n = s;
}

__global__ void scan_final(const int* __restrict__ cnt, const int* __restrict__ boff,
                           int* __restrict__ row_ptr, int n) {
  __shared__ int sums[NTHREADS];
  int b = blockIdx.x, t = threadIdx.x;
  int base = b * SCAN_CHUNK + t * 4;
  int v[4];
  int s = 0;
#pragma unroll
  for (int i = 0; i < 4; ++i) { int idx = base + i; v[i] = (idx < n) ? cnt[idx] : 0; s += v[i]; }
  sums[t] = s;
  __syncthreads();
  for (int off = 1; off < NTHREADS; off <<= 1) {
    int a = (t >= off) ? sums[t - off] : 0;
    __syncthreads();
    sums[t] += a;
    __syncthreads();
  }
  int run = boff[b] + sums[t] - s;
#pragma unroll
  for (int i = 0; i < 4; ++i) {
    int idx = base + i;
    if (idx < n) row_ptr[idx] = run;
    run += v[i];
  }
}

__global__ void scatter_edges(const int* __restrict__ row, const int* __restrict__ col,
                              const float* __restrict__ dinv, int* cursor,
                              int* __restrict__ src, float* __restrict__ wgt, int E) {
  int e = blockIdx.x * NTHREADS + threadIdx.x;
  if (e >= E) return;
  int r = row[e], c = col[e];
  int p = atomicAdd(&cursor[c], 1);
  src[p] = r;
  wgt[p] = dinv[r] * dinv[c];
}

// ---------------- weight pack: MFMA B-fragment order, bf16 ----------------

__global__ void pack_weights(const float* __restrict__ w_ih, const float* __restrict__ w_hh,
                             unsigned short* __restrict__ out) {
  int idx = blockIdx.x * NTHREADS + threadIdx.x;
  if (idx >= 491520) return;
  int e = idx & 7;
  int lane = (idx >> 3) & 63;
  int ft = (idx >> 9) & 7;
  int v = idx >> 12;
  int g = v % 6;
  int u = v / 6;
  int ks = u & 3;
  int layer = u >> 2;
  int k = 32 * ks + (e & 3) + 4 * ((lane >> 4) & 3) + 16 * (e >> 2);
  int j = 16 * ft + (lane & 15);
  const float* src = (g < 3) ? w_ih : w_hh;
  int gate = g % 3;
  float val = src[(size_t)layer * 49152 + (size_t)(gate * 128 + j) * 128 + k];
  out[idx] = f2bf(val);
}

// in [64][128] -> out [128][64]
__global__ void transpose_wh(const float* __restrict__ in, float* __restrict__ out) {
  int idx = blockIdx.x * NTHREADS + threadIdx.x;
  if (idx >= 8192) return;
  int k = idx >> 6, i = idx & 63;
  out[idx] = in[i * 128 + k];
}

// ---------------- encoder ----------------

__global__ void encoder(const float* __restrict__ x, const float* __restrict__ W,
                        const float* __restrict__ b, float* __restrict__ h,
                        unsigned short* __restrict__ hb, unsigned short* __restrict__ zmaxb,
                        int n) {
  int node = blockIdx.x * 4 + (threadIdx.x >> 6);
  int lane = threadIdx.x & 63;
  if (node >= n) return;
  float x0 = x[node * 3 + 0], x1 = x[node * 3 + 1], x2 = x[node * 3 + 2];
  int j0 = lane, j1 = lane + 64;
  float v0 = fmaxf(fmaf(W[j0 * 3 + 2], x2, fmaf(W[j0 * 3 + 1], x1, fmaf(W[j0 * 3], x0, b[j0]))), 0.f);
  float v1 = fmaxf(fmaf(W[j1 * 3 + 2], x2, fmaf(W[j1 * 3 + 1], x1, fmaf(W[j1 * 3], x0, b[j1]))), 0.f);
  float ss = v0 * v0 + v1 * v1;
#pragma unroll
  for (int sh = 32; sh > 0; sh >>= 1) ss += __shfl_down(ss, sh);
  ss = __shfl(ss, 0);
  float sc = 1.0f / fmaxf(sqrtf(ss), 1e-12f);
  size_t base = (size_t)node * 128;
  float o0 = v0 * sc, o1 = v1 * sc;
  h[base + j0] = o0;
  h[base + j1] = o1;
  unsigned short u0 = f2bf(o0), u1 = f2bf(o1);
  hb[base + j0] = u0;
  hb[base + j1] = u1;
  zmaxb[base + j0] = u0;
  zmaxb[base + j1] = u1;
}

// ---------------- aggregation: 8 gathers in flight, 4 FMA chains ----------------

__global__ void aggregate(const int* __restrict__ row_ptr, const int* __restrict__ src,
                          const float* __restrict__ wgt, const unsigned short* __restrict__ hb,
                          unsigned short* __restrict__ aggb, int n) {
  int node = blockIdx.x * 4 + (threadIdx.x >> 6);
  int lane = threadIdx.x & 63;
  if (node >= n) return;
  const unsigned* hw = (const unsigned*)hb;
  int pb = row_ptr[node], pe = row_ptr[node + 1];
  float aL[4] = {0.f, 0.f, 0.f, 0.f};
  float aH[4] = {0.f, 0.f, 0.f, 0.f};
  int p = pb;
  for (; p + 8 <= pe; p += 8) {
    unsigned u[8]; float w[8];
#pragma unroll
    for (int i = 0; i < 8; ++i) {
      int s = src[p + i];
      w[i] = wgt[p + i];
      u[i] = hw[(size_t)s * 64 + lane];
    }
#pragma unroll
    for (int i = 0; i < 8; ++i) {
      aL[i & 3] = fmaf(w[i], bf2f((unsigned short)(u[i] & 0xFFFFu)), aL[i & 3]);
      aH[i & 3] = fmaf(w[i], bf2f((unsigned short)(u[i] >> 16)), aH[i & 3]);
    }
  }
  if (p + 4 <= pe) {
    unsigned u[4]; float w[4];
#pragma unroll
    for (int i = 0; i < 4; ++i) {
      int s = src[p + i];
      w[i] = wgt[p + i];
      u[i] = hw[(size_t)s * 64 + lane];
    }
#pragma unroll
    for (int i = 0; i < 4; ++i) {
      aL[i] = fmaf(w[i], bf2f((unsigned short)(u[i] & 0xFFFFu)), aL[i]);
      aH[i] = fmaf(w[i], bf2f((unsigned short)(u[i] >> 16)), aH[i]);
    }
    p += 4;
  }
  for (; p < pe; ++p) {
    int s = src[p];
    float w = wgt[p];
    unsigned u = hw[(size_t)s * 64 + lane];
    aL[0] = fmaf(w, bf2f((unsigned short)(u & 0xFFFFu)), aL[0]);
    aH[0] = fmaf(w, bf2f((unsigned short)(u >> 16)), aH[0]);
  }
  float a0 = (aL[0] + aL[1]) + (aL[2] + aL[3]);
  float a1 = (aH[0] + aH[1]) + (aH[2] + aH[3]);
  unsigned o = ((unsigned)f2bf(a1) << 16) | (unsigned)f2bf(a0);
  ((unsigned*)(aggb + (size_t)node * 128))[lane] = o;
}

// ---------------- fused GRU layer via MFMA ----------------
// 1024 threads = 16 waves. Block: 64 nodes x 128 features x 6 gate-GEMMs, K=128.

__global__ __launch_bounds__(1024) void gru_mfma(
    const unsigned short* __restrict__ aggb, unsigned short* __restrict__ hb,
    float* __restrict__ h, unsigned short* __restrict__ zmaxb,
    const int4* __restrict__ wpk, const float* __restrict__ bih,
    const float* __restrict__ bhh, int n) {
  __shared__ unsigned short aggS[64 * 132];
  __shared__ unsigned short hS[64 * 132];
  __shared__ float partS[64 * 8];
  __shared__ float scv[64];
  int tid = threadIdx.x;
  int base = blockIdx.x * 64;

#pragma unroll
  for (int rep = 0; rep < 2; ++rep) {
    int idx = tid + rep * 1024;
    int row = idx >> 5, c4 = idx & 31;
    int gr = base + row; if (gr > n - 1) gr = n - 1;
    ushort4 ua = *(const ushort4*)(aggb + (size_t)gr * 128 + c4 * 4);
    ushort4 uh = *(const ushort4*)(hb + (size_t)gr * 128 + c4 * 4);
    *(ushort4*)&aggS[row * 132 + c4 * 4] = ua;
    *(ushort4*)&hS[row * 132 + c4 * 4] = uh;
  }
  __syncthreads();

  int w = tid >> 6, l = tid & 63;
  int mh = w & 1, fh = w >> 1;
  int lr = l & 15, lg = l >> 4;

  f32x4 acc[2][6];
#pragma unroll
  for (int mt = 0; mt < 2; ++mt)
#pragma unroll
    for (int g = 0; g < 6; ++g) { acc[mt][g][0] = 0.f; acc[mt][g][1] = 0.f; acc[mt][g][2] = 0.f; acc[mt][g][3] = 0.f; }

#pragma unroll
  for (int ks = 0; ks < 4; ++ks) {
    U8 fa[2], fhh[2];
#pragma unroll
    for (int mt = 0; mt < 2; ++mt) {
      int boff = (mh * 32 + mt * 16 + lr) * 132 + ks * 32 + lg * 4;
      fa[mt].h[0] = *(const ushort4*)&aggS[boff];
      fa[mt].h[1] = *(const ushort4*)&aggS[boff + 16];
      fhh[mt].h[0] = *(const ushort4*)&hS[boff];
      fhh[mt].h[1] = *(const ushort4*)&hS[boff + 16];
    }
#pragma unroll
    for (int g = 0; g < 6; ++g) {
      U8 bw; bw.q = wpk[((ks * 6 + g) * 8 + fh) * 64 + l];
      const U8& a0 = (g < 3) ? fa[0] : fhh[0];
      const U8& a1 = (g < 3) ? fa[1] : fhh[1];
      acc[0][g] = __builtin_amdgcn_mfma_f32_16x16x32_bf16(a0.v, bw.v, acc[0][g], 0, 0, 0);
      acc[1][g] = __builtin_amdgcn_mfma_f32_16x16x32_bf16(a1.v, bw.v, acc[1][g], 0, 0, 0);
    }
  }

  int jj = fh * 16 + lr;
  float br = bih[jj], bz = bih[128 + jj], bn = bih[256 + jj];
  float cr = bhh[jj], cz = bhh[128 + jj], cn = bhh[256 + jj];
  float hn_out[2][4];
#pragma unroll
  for (int mt = 0; mt < 2; ++mt)
#pragma unroll
    for (int e = 0; e < 4; ++e) {
      int row = mh * 32 + mt * 16 + lg * 4 + e;
      float ir = acc[mt][0][e], iz = acc[mt][1][e], inn = acc[mt][2][e];
      float hr = acc[mt][3][e], hz = acc[mt][4][e], hnv = acc[mt][5][e];
      float r = 1.f / (1.f + __expf(-(ir + hr + br + cr)));
      float z = 1.f / (1.f + __expf(-(iz + hz + bz + cz)));
      float ng = tanhf(inn + bn + r * (hnv + cn));
      int gr = base + row; int cgr = (gr > n - 1) ? (n - 1) : gr;
      float hv = h[(size_t)cgr * 128 + jj];
      float hn = (1.f - z) * ng + z * hv;
      hn_out[mt][e] = hn;
      float p = hn * hn;
      p += __shfl_xor(p, 1);
      p += __shfl_xor(p, 2);
      p += __shfl_xor(p, 4);
      p += __shfl_xor(p, 8);
      if (lr == 0) partS[row * 8 + fh] = p;
    }
  __syncthreads();
  if (tid < 64) {
    float ss = 0.f;
#pragma unroll
    for (int f = 0; f < 8; ++f) ss += partS[tid * 8 + f];
    scv[tid] = 1.f / fmaxf(sqrtf(ss), 1e-12f);
  }
  __syncthreads();
#pragma unroll
  for (int mt = 0; mt < 2; ++mt)
#pragma unroll
    for (int e = 0; e < 4; ++e) {
      int row = mh * 32 + mt * 16 + lg * 4 + e;
      int gr = base + row;
      if (gr < n) {
        float v = hn_out[mt][e] * scv[row];
        size_t o = (size_t)gr * 128 + jj;
        h[o] = v;
        unsigned short ub = f2bf(v);
        hb[o] = ub;
        unsigned short zold = zmaxb[o];
        zmaxb[o] = (bf2f(ub) > bf2f(zold)) ? ub : zold;
      }
    }
}

// ---------------- decoder ----------------

__global__ void decoder(const unsigned short* __restrict__ zb, const float* __restrict__ WhT,
                        const float* __restrict__ bh, const float* __restrict__ Wo,
                        const float* __restrict__ bo, float* __restrict__ out, int n) {
  __shared__ float zS[4][128];
  int wv = threadIdx.x >> 6, lane = threadIdx.x & 63;
  int node = blockIdx.x * 4 + wv;
  if (node >= n) return;  // grid exact for N=50000
  unsigned u = ((const unsigned*)(zb + (size_t)node * 128))[lane];
  zS[wv][lane * 2] = bf2f((unsigned short)(u & 0xFFFFu));
  zS[wv][lane * 2 + 1] = bf2f((unsigned short)(u >> 16));
  __syncthreads();
  float acc = bh[lane];
#pragma unroll 4
  for (int k = 0; k < 128; ++k) acc = fmaf(zS[wv][k], WhT[k * 64 + lane], acc);
  float hid = fmaxf(acc, 0.f);
  float val = hid * Wo[lane];
#pragma unroll
  for (int sh = 32; sh > 0; sh >>= 1) val += __shfl_down(val, sh);
  if (lane == 0) out[node] = val + bo[0];
}

// ---------------- launch ----------------

extern "C" void kernel_launch(void* const* d_in, const int* in_sizes, int n_in,
                              void* d_out, int out_size, void* d_ws, size_t ws_size,
                              hipStream_t stream) {
  const float* x       = (const float*)d_in[0];
  const int*   edge    = (const int*)d_in[1];
  const float* W_embed = (const float*)d_in[2];
  const float* b_embed = (const float*)d_in[3];
  const float* w_ih    = (const float*)d_in[4];
  const float* w_hh    = (const float*)d_in[5];
  const float* b_ih    = (const float*)d_in[6];
  const float* b_hh    = (const float*)d_in[7];
  const float* W_hid   = (const float*)d_in[8];
  const float* b_hid   = (const float*)d_in[9];
  const float* W_out   = (const float*)d_in[10];
  const float* b_out   = (const float*)d_in[11];
  float* out = (float*)d_out;

  const int N = in_sizes[0] / 3;       // 50000
  const int E = in_sizes[1] / 2;       // 600000
  const int NB = (N + SCAN_CHUNK - 1) / SCAN_CHUNK;

  char* ws = (char*)d_ws;
  size_t off = 0;
  auto alloc = [&](size_t bytes) -> void* {
    void* p = ws + off;
    off = (off + bytes + 511) & ~(size_t)511;
    return p;
  };
  int*   deg     = (int*)alloc((size_t)N * 4);
  float* dinv    = (float*)alloc((size_t)N * 4);
  int*   row_ptr = (int*)alloc((size_t)(N + 1) * 4);
  int*   cursor  = (int*)alloc((size_t)N * 4);
  int*   bsum    = (int*)alloc((size_t)NB * 4);
  int*   boff    = (int*)alloc((size_t)NB * 4);
  int*   srcv    = (int*)alloc((size_t)E * 4);
  float* wgtv    = (float*)alloc((size_t)E * 4);
  unsigned short* wpack = (unsigned short*)alloc((size_t)491520 * 2);
  float* WhT     = (float*)alloc((size_t)8192 * 4);
  float* h       = (float*)alloc((size_t)N * 128 * 4);
  unsigned short* hb    = (unsigned short*)alloc((size_t)N * 128 * 2);
  unsigned short* aggb  = (unsigned short*)alloc((size_t)N * 128 * 2);
  unsigned short* zmaxb = (unsigned short*)alloc((size_t)N * 128 * 2);

  const int* erow = edge;
  const int* ecol = edge + E;

  hipMemsetAsync(deg, 0, (size_t)N * 4, stream);
  count_deg<<<(E + NTHREADS - 1) / NTHREADS, NTHREADS, 0, stream>>>(ecol, deg, E);
  compute_dinv<<<(N + NTHREADS - 1) / NTHREADS, NTHREADS, 0, stream>>>(deg, dinv, N);
  block_reduce<<<NB, NTHREADS, 0, stream>>>(deg, bsum, N);
  scan_partials<<<1, 64, 0, stream>>>(bsum, boff, row_ptr + N, NB);
  scan_final<<<NB, NTHREADS, 0, stream>>>(deg, boff, row_ptr, N);
  hipMemcpyAsync(cursor, row_ptr, (size_t)N * 4, hipMemcpyDeviceToDevice, stream);
  scatter_edges<<<(E + NTHREADS - 1) / NTHREADS, NTHREADS, 0, stream>>>(erow, ecol, dinv, cursor, srcv, wgtv, E);

  pack_weights<<<(491520 + NTHREADS - 1) / NTHREADS, NTHREADS, 0, stream>>>(w_ih, w_hh, wpack);
  transpose_wh<<<32, NTHREADS, 0, stream>>>(W_hid, WhT);

  encoder<<<(N + 3) / 4, NTHREADS, 0, stream>>>(x, W_embed, b_embed, h, hb, zmaxb, N);

  for (int l = 0; l < 5; ++l) {
    aggregate<<<(N + 3) / 4, NTHREADS, 0, stream>>>(row_ptr, srcv, wgtv, hb, aggb, N);
    gru_mfma<<<(N + 63) / 64, 1024, 0, stream>>>(
        aggb, hb, h, zmaxb, (const int4*)(wpack + (size_t)l * 98304),
        b_ih + (size_t)l * 384, b_hh + (size_t)l * 384, N);
  }

  decoder<<<(N + 3) / 4, NTHREADS, 0, stream>>>(zmaxb, WhT, b_hid, W_out, b_out, out, N);
}

// Round 5
// 508.929 us; speedup vs baseline: 3.2231x; 1.0805x over previous
//
#include <hip/hip_runtime.h>
#include <math.h>

// DrBC: encoder -> 5x(GCN-aggregate(bf16, unrolled) + GRU(MFMA bf16) + l2norm,
// running max bf16) -> decoder(MFMA bf16 stage1 + fused fp32 stage2).

#define NTHREADS 256
#define SCAN_CHUNK 1024

typedef __attribute__((ext_vector_type(8))) short s16x8;
typedef __attribute__((ext_vector_type(4))) float f32x4;

union U8 { s16x8 v; ushort4 h[2]; int4 q; };

__device__ __forceinline__ unsigned short f2bf(float f) {
  union { float f; unsigned u; } x; x.f = f;
  unsigned u = x.u + 0x7FFFu + ((x.u >> 16) & 1u);  // RNE to bf16
  return (unsigned short)(u >> 16);
}
__device__ __forceinline__ float bf2f(unsigned short s) {
  union { unsigned u; float f; } x; x.u = ((unsigned)s) << 16;
  return x.f;
}

// ---------------- CSR build ----------------

__global__ void count_deg(const int* __restrict__ col, int* deg, int E) {
  int e = blockIdx.x * NTHREADS + threadIdx.x;
  if (e < E) atomicAdd(&deg[col[e]], 1);
}

__global__ void compute_dinv(const int* __restrict__ deg, float* __restrict__ dinv, int n) {
  int i = blockIdx.x * NTHREADS + threadIdx.x;
  if (i < n) dinv[i] = rsqrtf((float)deg[i] + 1.0f);
}

__global__ void block_reduce(const int* __restrict__ cnt, int* __restrict__ bsum, int n) {
  __shared__ int red[NTHREADS];
  int b = blockIdx.x, t = threadIdx.x;
  int base = b * SCAN_CHUNK + t * 4;
  int s = 0;
#pragma unroll
  for (int i = 0; i < 4; ++i) { int idx = base + i; if (idx < n) s += cnt[idx]; }
  red[t] = s;
  __syncthreads();
  for (int off = NTHREADS / 2; off > 0; off >>= 1) {
    if (t < off) red[t] += red[t + off];
    __syncthreads();
  }
  if (t == 0) bsum[b] = red[0];
}

// 64 threads (1 wave); nb <= 64.
__global__ void scan_partials(const int* __restrict__ bsum, int* __restrict__ boff,
                              int* __restrict__ row_ptr_n, int nb) {
  int t = threadIdx.x;
  int s = (t < nb) ? bsum[t] : 0;
  int orig = s;
#pragma unroll
  for (int off = 1; off < 64; off <<= 1) {
    int v = __shfl_up(s, off);
    if (t >= off) s += v;
  }
  if (t < nb) boff[t] = s - orig;
  if (t == nb - 1) *row_ptr_n = s;
}

__global__ void scan_final(const int* __restrict__ cnt, const int* __restrict__ boff,
                           int* __restrict__ row_ptr, int n) {
  __shared__ int sums[NTHREADS];
  int b = blockIdx.x, t = threadIdx.x;
  int base = b * SCAN_CHUNK + t * 4;
  int v[4];
  int s = 0;
#pragma unroll
  for (int i = 0; i < 4; ++i) { int idx = base + i; v[i] = (idx < n) ? cnt[idx] : 0; s += v[i]; }
  sums[t] = s;
  __syncthreads();
  for (int off = 1; off < NTHREADS; off <<= 1) {
    int a = (t >= off) ? sums[t - off] : 0;
    __syncthreads();
    sums[t] += a;
    __syncthreads();
  }
  int run = boff[b] + sums[t] - s;
#pragma unroll
  for (int i = 0; i < 4; ++i) {
    int idx = base + i;
    if (idx < n) row_ptr[idx] = run;
    run += v[i];
  }
}

__global__ void scatter_edges(const int* __restrict__ row, const int* __restrict__ col,
                              const float* __restrict__ dinv, int* cursor,
                              int* __restrict__ src, float* __restrict__ wgt, int E) {
  int e = blockIdx.x * NTHREADS + threadIdx.x;
  if (e >= E) return;
  int r = row[e], c = col[e];
  int p = atomicAdd(&cursor[c], 1);
  src[p] = r;
  wgt[p] = dinv[r] * dinv[c];
}

// ---------------- weight packs: MFMA B-fragment order, bf16 ----------------
// k-map sigma(e,lane) = 32*ks + (e&3) + 4*((lane>>4)&3) + 16*(e>>2); same map used on
// the A side -> result invariant to sigma's exact correctness.

__global__ void pack_weights(const float* __restrict__ w_ih, const float* __restrict__ w_hh,
                             unsigned short* __restrict__ out) {
  int idx = blockIdx.x * NTHREADS + threadIdx.x;
  if (idx >= 491520) return;
  int e = idx & 7;
  int lane = (idx >> 3) & 63;
  int ft = (idx >> 9) & 7;
  int v = idx >> 12;
  int g = v % 6;
  int u = v / 6;
  int ks = u & 3;
  int layer = u >> 2;
  int k = 32 * ks + (e & 3) + 4 * ((lane >> 4) & 3) + 16 * (e >> 2);
  int j = 16 * ft + (lane & 15);
  const float* src = (g < 3) ? w_ih : w_hh;
  int gate = g % 3;
  float val = src[(size_t)layer * 49152 + (size_t)(gate * 128 + j) * 128 + k];
  out[idx] = f2bf(val);
}

// W_hid [64][128] -> [ks 0..3][ft 0..3][lane 0..63][e 0..7] bf16 (8192 elems)
__global__ void pack_whid(const float* __restrict__ W_hid, unsigned short* __restrict__ out) {
  int idx = blockIdx.x * NTHREADS + threadIdx.x;
  if (idx >= 8192) return;
  int e = idx & 7;
  int lane = (idx >> 3) & 63;
  int ft = (idx >> 9) & 3;
  int ks = idx >> 11;
  int k = 32 * ks + (e & 3) + 4 * ((lane >> 4) & 3) + 16 * (e >> 2);
  int j = 16 * ft + (lane & 15);
  out[idx] = f2bf(W_hid[j * 128 + k]);
}

// ---------------- encoder ----------------

__global__ void encoder(const float* __restrict__ x, const float* __restrict__ W,
                        const float* __restrict__ b, float* __restrict__ h,
                        unsigned short* __restrict__ hb, unsigned short* __restrict__ zmaxb,
                        int n) {
  int node = blockIdx.x * 4 + (threadIdx.x >> 6);
  int lane = threadIdx.x & 63;
  if (node >= n) return;
  float x0 = x[node * 3 + 0], x1 = x[node * 3 + 1], x2 = x[node * 3 + 2];
  int j0 = lane, j1 = lane + 64;
  float v0 = fmaxf(fmaf(W[j0 * 3 + 2], x2, fmaf(W[j0 * 3 + 1], x1, fmaf(W[j0 * 3], x0, b[j0]))), 0.f);
  float v1 = fmaxf(fmaf(W[j1 * 3 + 2], x2, fmaf(W[j1 * 3 + 1], x1, fmaf(W[j1 * 3], x0, b[j1]))), 0.f);
  float ss = v0 * v0 + v1 * v1;
#pragma unroll
  for (int sh = 32; sh > 0; sh >>= 1) ss += __shfl_down(ss, sh);
  ss = __shfl(ss, 0);
  float sc = 1.0f / fmaxf(sqrtf(ss), 1e-12f);
  size_t base = (size_t)node * 128;
  float o0 = v0 * sc, o1 = v1 * sc;
  h[base + j0] = o0;
  h[base + j1] = o1;
  unsigned short u0 = f2bf(o0), u1 = f2bf(o1);
  hb[base + j0] = u0;
  hb[base + j1] = u1;
  zmaxb[base + j0] = u0;
  zmaxb[base + j1] = u1;
}

// ---------------- aggregation: 8 gathers in flight, 4 FMA chains ----------------

__global__ void aggregate(const int* __restrict__ row_ptr, const int* __restrict__ src,
                          const float* __restrict__ wgt, const unsigned short* __restrict__ hb,
                          unsigned short* __restrict__ aggb, int n) {
  int node = blockIdx.x * 4 + (threadIdx.x >> 6);
  int lane = threadIdx.x & 63;
  if (node >= n) return;
  const unsigned* hw = (const unsigned*)hb;
  int pb = row_ptr[node], pe = row_ptr[node + 1];
  float aL[4] = {0.f, 0.f, 0.f, 0.f};
  float aH[4] = {0.f, 0.f, 0.f, 0.f};
  int p = pb;
  for (; p + 8 <= pe; p += 8) {
    unsigned u[8]; float w[8];
#pragma unroll
    for (int i = 0; i < 8; ++i) {
      int s = src[p + i];
      w[i] = wgt[p + i];
      u[i] = hw[(size_t)s * 64 + lane];
    }
#pragma unroll
    for (int i = 0; i < 8; ++i) {
      aL[i & 3] = fmaf(w[i], bf2f((unsigned short)(u[i] & 0xFFFFu)), aL[i & 3]);
      aH[i & 3] = fmaf(w[i], bf2f((unsigned short)(u[i] >> 16)), aH[i & 3]);
    }
  }
  if (p + 4 <= pe) {
    unsigned u[4]; float w[4];
#pragma unroll
    for (int i = 0; i < 4; ++i) {
      int s = src[p + i];
      w[i] = wgt[p + i];
      u[i] = hw[(size_t)s * 64 + lane];
    }
#pragma unroll
    for (int i = 0; i < 4; ++i) {
      aL[i] = fmaf(w[i], bf2f((unsigned short)(u[i] & 0xFFFFu)), aL[i]);
      aH[i] = fmaf(w[i], bf2f((unsigned short)(u[i] >> 16)), aH[i]);
    }
    p += 4;
  }
  for (; p < pe; ++p) {
    int s = src[p];
    float w = wgt[p];
    unsigned u = hw[(size_t)s * 64 + lane];
    aL[0] = fmaf(w, bf2f((unsigned short)(u & 0xFFFFu)), aL[0]);
    aH[0] = fmaf(w, bf2f((unsigned short)(u >> 16)), aH[0]);
  }
  float a0 = (aL[0] + aL[1]) + (aL[2] + aL[3]);
  float a1 = (aH[0] + aH[1]) + (aH[2] + aH[3]);
  unsigned o = ((unsigned)f2bf(a1) << 16) | (unsigned)f2bf(a0);
  ((unsigned*)(aggb + (size_t)node * 128))[lane] = o;
}

// ---------------- fused GRU layer via MFMA ----------------
// 1024 threads = 16 waves. Block: 64 nodes x 128 features x 6 gate-GEMMs, K=128.

__global__ __launch_bounds__(1024) void gru_mfma(
    const unsigned short* __restrict__ aggb, unsigned short* __restrict__ hb,
    float* __restrict__ h, unsigned short* __restrict__ zmaxb,
    const int4* __restrict__ wpk, const float* __restrict__ bih,
    const float* __restrict__ bhh, int n) {
  __shared__ unsigned short aggS[64 * 132];
  __shared__ unsigned short hS[64 * 132];
  __shared__ float partS[64 * 8];
  __shared__ float scv[64];
  int tid = threadIdx.x;
  int base = blockIdx.x * 64;

#pragma unroll
  for (int rep = 0; rep < 2; ++rep) {
    int idx = tid + rep * 1024;
    int row = idx >> 5, c4 = idx & 31;
    int gr = base + row; if (gr > n - 1) gr = n - 1;
    ushort4 ua = *(const ushort4*)(aggb + (size_t)gr * 128 + c4 * 4);
    ushort4 uh = *(const ushort4*)(hb + (size_t)gr * 128 + c4 * 4);
    *(ushort4*)&aggS[row * 132 + c4 * 4] = ua;
    *(ushort4*)&hS[row * 132 + c4 * 4] = uh;
  }
  __syncthreads();

  int w = tid >> 6, l = tid & 63;
  int mh = w & 1, fh = w >> 1;
  int lr = l & 15, lg = l >> 4;

  f32x4 acc[2][6];
#pragma unroll
  for (int mt = 0; mt < 2; ++mt)
#pragma unroll
    for (int g = 0; g < 6; ++g) { acc[mt][g][0] = 0.f; acc[mt][g][1] = 0.f; acc[mt][g][2] = 0.f; acc[mt][g][3] = 0.f; }

#pragma unroll
  for (int ks = 0; ks < 4; ++ks) {
    U8 fa[2], fhh[2];
#pragma unroll
    for (int mt = 0; mt < 2; ++mt) {
      int boff = (mh * 32 + mt * 16 + lr) * 132 + ks * 32 + lg * 4;
      fa[mt].h[0] = *(const ushort4*)&aggS[boff];
      fa[mt].h[1] = *(const ushort4*)&aggS[boff + 16];
      fhh[mt].h[0] = *(const ushort4*)&hS[boff];
      fhh[mt].h[1] = *(const ushort4*)&hS[boff + 16];
    }
#pragma unroll
    for (int g = 0; g < 6; ++g) {
      U8 bw; bw.q = wpk[((ks * 6 + g) * 8 + fh) * 64 + l];
      const U8& a0 = (g < 3) ? fa[0] : fhh[0];
      const U8& a1 = (g < 3) ? fa[1] : fhh[1];
      acc[0][g] = __builtin_amdgcn_mfma_f32_16x16x32_bf16(a0.v, bw.v, acc[0][g], 0, 0, 0);
      acc[1][g] = __builtin_amdgcn_mfma_f32_16x16x32_bf16(a1.v, bw.v, acc[1][g], 0, 0, 0);
    }
  }

  int jj = fh * 16 + lr;
  float br = bih[jj], bz = bih[128 + jj], bn = bih[256 + jj];
  float cr = bhh[jj], cz = bhh[128 + jj], cn = bhh[256 + jj];
  float hn_out[2][4];
#pragma unroll
  for (int mt = 0; mt < 2; ++mt)
#pragma unroll
    for (int e = 0; e < 4; ++e) {
      int row = mh * 32 + mt * 16 + lg * 4 + e;
      float ir = acc[mt][0][e], iz = acc[mt][1][e], inn = acc[mt][2][e];
      float hr = acc[mt][3][e], hz = acc[mt][4][e], hnv = acc[mt][5][e];
      float r = 1.f / (1.f + __expf(-(ir + hr + br + cr)));
      float z = 1.f / (1.f + __expf(-(iz + hz + bz + cz)));
      float ng = tanhf(inn + bn + r * (hnv + cn));
      int gr = base + row; int cgr = (gr > n - 1) ? (n - 1) : gr;
      float hv = h[(size_t)cgr * 128 + jj];
      float hn = (1.f - z) * ng + z * hv;
      hn_out[mt][e] = hn;
      float p = hn * hn;
      p += __shfl_xor(p, 1);
      p += __shfl_xor(p, 2);
      p += __shfl_xor(p, 4);
      p += __shfl_xor(p, 8);
      if (lr == 0) partS[row * 8 + fh] = p;
    }
  __syncthreads();
  if (tid < 64) {
    float ss = 0.f;
#pragma unroll
    for (int f = 0; f < 8; ++f) ss += partS[tid * 8 + f];
    scv[tid] = 1.f / fmaxf(sqrtf(ss), 1e-12f);
  }
  __syncthreads();
#pragma unroll
  for (int mt = 0; mt < 2; ++mt)
#pragma unroll
    for (int e = 0; e < 4; ++e) {
      int row = mh * 32 + mt * 16 + lg * 4 + e;
      int gr = base + row;
      if (gr < n) {
        float v = hn_out[mt][e] * scv[row];
        size_t o = (size_t)gr * 128 + jj;
        h[o] = v;
        unsigned short ub = f2bf(v);
        hb[o] = ub;
        unsigned short zold = zmaxb[o];
        zmaxb[o] = (bf2f(ub) > bf2f(zold)) ? ub : zold;
      }
    }
}

// ---------------- decoder: MFMA stage1 (z@W_hid^T) + fused relu*Wo reduce ----------------
// 256 threads = 4 waves, 64 nodes/block. Wave w: m-tile rows w*16..+16, all 4 ft tiles.

__global__ __launch_bounds__(256) void decoder_mfma(
    const unsigned short* __restrict__ zb, const int4* __restrict__ wdpk,
    const float* __restrict__ bh, const float* __restrict__ Wo,
    const float* __restrict__ bo, float* __restrict__ out, int n) {
  __shared__ unsigned short zS[64 * 132];
  int tid = threadIdx.x;
  int base = blockIdx.x * 64;
#pragma unroll
  for (int rep = 0; rep < 8; ++rep) {
    int idx = tid + rep * 256;
    int row = idx >> 5, c4 = idx & 31;
    int gr = base + row; if (gr > n - 1) gr = n - 1;
    ushort4 uz = *(const ushort4*)(zb + (size_t)gr * 128 + c4 * 4);
    *(ushort4*)&zS[row * 132 + c4 * 4] = uz;
  }
  __syncthreads();
  int w = tid >> 6, l = tid & 63;
  int lr = l & 15, lg = l >> 4;
  f32x4 acc[4];
#pragma unroll
  for (int ft = 0; ft < 4; ++ft) { acc[ft][0] = 0.f; acc[ft][1] = 0.f; acc[ft][2] = 0.f; acc[ft][3] = 0.f; }
#pragma unroll
  for (int ks = 0; ks < 4; ++ks) {
    U8 fz;
    int boff = (w * 16 + lr) * 132 + ks * 32 + lg * 4;
    fz.h[0] = *(const ushort4*)&zS[boff];
    fz.h[1] = *(const ushort4*)&zS[boff + 16];
#pragma unroll
    for (int ft = 0; ft < 4; ++ft) {
      U8 bw; bw.q = wdpk[(ks * 4 + ft) * 64 + l];
      acc[ft] = __builtin_amdgcn_mfma_f32_16x16x32_bf16(fz.v, bw.v, acc[ft], 0, 0, 0);
    }
  }
  // epilogue: s[e] = sum_ft relu(acc+bh)*Wo ; reduce over 16-lane group (j partials)
  float s[4] = {0.f, 0.f, 0.f, 0.f};
#pragma unroll
  for (int ft = 0; ft < 4; ++ft) {
    int j = ft * 16 + lr;
    float bj = bh[j], wj = Wo[j];
#pragma unroll
    for (int e = 0; e < 4; ++e) {
      float hid = fmaxf(acc[ft][e] + bj, 0.f);
      s[e] = fmaf(hid, wj, s[e]);
    }
  }
#pragma unroll
  for (int e = 0; e < 4; ++e) {
    float v = s[e];
    v += __shfl_xor(v, 1);
    v += __shfl_xor(v, 2);
    v += __shfl_xor(v, 4);
    v += __shfl_xor(v, 8);
    if (lr == 0) {
      int gr = base + w * 16 + lg * 4 + e;
      if (gr < n) out[gr] = v + bo[0];
    }
  }
}

// ---------------- launch ----------------

extern "C" void kernel_launch(void* const* d_in, const int* in_sizes, int n_in,
                              void* d_out, int out_size, void* d_ws, size_t ws_size,
                              hipStream_t stream) {
  const float* x       = (const float*)d_in[0];
  const int*   edge    = (const int*)d_in[1];
  const float* W_embed = (const float*)d_in[2];
  const float* b_embed = (const float*)d_in[3];
  const float* w_ih    = (const float*)d_in[4];
  const float* w_hh    = (const float*)d_in[5];
  const float* b_ih    = (const float*)d_in[6];
  const float* b_hh    = (const float*)d_in[7];
  const float* W_hid   = (const float*)d_in[8];
  const float* b_hid   = (const float*)d_in[9];
  const float* W_out   = (const float*)d_in[10];
  const float* b_out   = (const float*)d_in[11];
  float* out = (float*)d_out;

  const int N = in_sizes[0] / 3;       // 50000
  const int E = in_sizes[1] / 2;       // 600000
  const int NB = (N + SCAN_CHUNK - 1) / SCAN_CHUNK;

  char* ws = (char*)d_ws;
  size_t off = 0;
  auto alloc = [&](size_t bytes) -> void* {
    void* p = ws + off;
    off = (off + bytes + 511) & ~(size_t)511;
    return p;
  };
  int*   deg     = (int*)alloc((size_t)N * 4);
  float* dinv    = (float*)alloc((size_t)N * 4);
  int*   row_ptr = (int*)alloc((size_t)(N + 1) * 4);
  int*   cursor  = (int*)alloc((size_t)N * 4);
  int*   bsum    = (int*)alloc((size_t)NB * 4);
  int*   boff    = (int*)alloc((size_t)NB * 4);
  int*   srcv    = (int*)alloc((size_t)E * 4);
  float* wgtv    = (float*)alloc((size_t)E * 4);
  unsigned short* wpack  = (unsigned short*)alloc((size_t)491520 * 2);
  unsigned short* wdpack = (unsigned short*)alloc((size_t)8192 * 2);
  float* h       = (float*)alloc((size_t)N * 128 * 4);
  unsigned short* hb    = (unsigned short*)alloc((size_t)N * 128 * 2);
  unsigned short* aggb  = (unsigned short*)alloc((size_t)N * 128 * 2);
  unsigned short* zmaxb = (unsigned short*)alloc((size_t)N * 128 * 2);

  const int* erow = edge;
  const int* ecol = edge + E;

  hipMemsetAsync(deg, 0, (size_t)N * 4, stream);
  count_deg<<<(E + NTHREADS - 1) / NTHREADS, NTHREADS, 0, stream>>>(ecol, deg, E);
  compute_dinv<<<(N + NTHREADS - 1) / NTHREADS, NTHREADS, 0, stream>>>(deg, dinv, N);
  block_reduce<<<NB, NTHREADS, 0, stream>>>(deg, bsum, N);
  scan_partials<<<1, 64, 0, stream>>>(bsum, boff, row_ptr + N, NB);
  scan_final<<<NB, NTHREADS, 0, stream>>>(deg, boff, row_ptr, N);
  hipMemcpyAsync(cursor, row_ptr, (size_t)N * 4, hipMemcpyDeviceToDevice, stream);
  scatter_edges<<<(E + NTHREADS - 1) / NTHREADS, NTHREADS, 0, stream>>>(erow, ecol, dinv, cursor, srcv, wgtv, E);

  pack_weights<<<(491520 + NTHREADS - 1) / NTHREADS, NTHREADS, 0, stream>>>(w_ih, w_hh, wpack);
  pack_whid<<<32, NTHREADS, 0, stream>>>(W_hid, wdpack);

  encoder<<<(N + 3) / 4, NTHREADS, 0, stream>>>(x, W_embed, b_embed, h, hb, zmaxb, N);

  for (int l = 0; l < 5; ++l) {
    aggregate<<<(N + 3) / 4, NTHREADS, 0, stream>>>(row_ptr, srcv, wgtv, hb, aggb, N);
    gru_mfma<<<(N + 63) / 64, 1024, 0, stream>>>(
        aggb, hb, h, zmaxb, (const int4*)(wpack + (size_t)l * 98304),
        b_ih + (size_t)l * 384, b_hh + (size_t)l * 384, N);
  }

  decoder_mfma<<<(N + 63) / 64, NTHREADS, 0, stream>>>(
      zmaxb, (const int4*)wdpack, b_hid, W_out, b_out, out, N);
}